// Round 13
// baseline (1948.840 us; speedup 1.0000x reference)
//
#include <hip/hip_runtime.h>
#include <hip/hip_fp16.h>

#define BB 128
#define TT 500
#define HH 512
#define TWOH 1024
#define KB 16  // k-tiles of 32

typedef _Float16 f16x8 __attribute__((ext_vector_type(8)));
typedef float f32x4 __attribute__((ext_vector_type(4)));
typedef unsigned long long u64;

// ws: u16 1 MiB | hx u32 [8 g][2 par][16 m][512 k] (512 KiB)
// hx word = (tag16 << 16) | fp16 h[m][k]   (tag = step, 0..500; 0xFFFF = inv)
#define WS_U16_HALVES (TWOH * HH)
#define HX_WORDS (8 * 2 * 16 * HH)

__global__ void prep_kernel(const float* __restrict__ u,
                            const float* __restrict__ ht,
                            __half* __restrict__ u16,
                            unsigned* __restrict__ hx) {
  int i = blockIdx.x * blockDim.x + threadIdx.x;
  if (i < WS_U16_HALVES) u16[i] = __float2half(u[i]);
  if (i < HX_WORDS) {
    int g = i >> 14, rem = i & 16383;
    int par = rem >> 13, m = (rem >> 9) & 15, k = rem & 511;
    unsigned val;
    if (par == 0) {  // h_0, tag 0 in high halfword
      int R = g * 16 + m;
      val = (unsigned)__half_as_ushort(__float2half(ht[(size_t)R * HH + k]));
    } else {
      val = 0xFFFF0000u;  // sentinel (never matches; replay-stale safe)
    }
    hx[i] = val;
  }
}

#define TAGMASK 0xFFFF0000FFFF0000ull

// 32 blocks x 512 threads (8 waves). Block b: group g=b&7 (16 batch rows),
// col-slice s=b>>3 (128 cols, both gates). One chain-phase per step; MALL
// (agent-scope) fused tag16+fp16 protocol — the cooperative tagged read IS
// the flag poll AND the payload fetch (proven R7/R10). R13: 4 producers per
// group (straggler max over 4, not 8) and double-buffered wx (HBM latency
// off the critical chain; producers' h-stores fire tightly synchronized).
__global__ __launch_bounds__(512, 1) void ligru_mfma(
    const float* __restrict__ wx, const __half* __restrict__ u16,
    const float* __restrict__ ht, const float* __restrict__ mask,
    float* __restrict__ out, unsigned* __restrict__ hx) {
  const int tid = threadIdx.x;
  const int lane = tid & 63;
  const int w = tid >> 6;   // 0..7
  const int l15 = lane & 15;
  const int q = lane >> 4;
  const int b = blockIdx.x;
  const int g = b & 7;   // group
  const int s = b >> 3;  // col-slice 0..3
  const int row0 = g * 16;
  const int j = s * 128 + w * 16 + l15;  // this lane's hidden col

  __shared__ alignas(16) char hsm[2][16 * 1024];  // [par][m][k] fp16, XOR-swz

  // B-frags (u), persistent (128 VGPR). nt0: gate row j (at); nt1: row 512+j.
  f16x8 bf[KB][2];
#pragma unroll
  for (int kb = 0; kb < KB; ++kb) {
    bf[kb][0] = *(const f16x8*)(u16 + (size_t)j * HH + kb * 32 + q * 8);
    bf[kb][1] = *(const f16x8*)(u16 + (size_t)(HH + j) * HH + kb * 32 + q * 8);
  }

  // per-lane persistent state: rows m=4q+r, col j; fp32 master h
  float hreg[4], mreg[4];
#pragma unroll
  for (int r = 0; r < 4; ++r) {
    size_t off = (size_t)(row0 + 4 * q + r) * HH + j;
    mreg[r] = mask[off];
    hreg[r] = ht[off];
  }

  const size_t BTH = (size_t)BB * TT * HH;
  float* out_h = out;
  float* out_z = out + BTH;
  float* out_a = out + 2 * BTH;
  float* out_hc = out + 3 * BTH;

  const u64* hxg = (const u64*)hx + ((size_t)g << 13);  // [2 par][4096 qw]
  const int mb = tid >> 8;    // payload rows this thread stages: mb + pp*2
  const int k2 = tid & 255;   // qword column within row

  // initial fetch: h(0), parity 0 (prep data, tag 0); 8 qwords/thread
  u64 qw[8];
#pragma unroll
  for (int pp = 0; pp < 8; ++pp)
    qw[pp] = __hip_atomic_load(hxg + (size_t)pp * 512 + tid, __ATOMIC_RELAXED,
                               __HIP_MEMORY_SCOPE_AGENT);

  // wx double buffer: cur holds step-t values, nxt is in flight for t+1
  float wxa[4], wxz[4], wxa_n[4], wxz_n[4];
#pragma unroll
  for (int r = 0; r < 4; ++r) {
    size_t base = ((size_t)(row0 + 4 * q + r) * TT + 0) * TWOH + j;
    wxa[r] = wx[base];
    wxz[r] = wx[base + HH];
  }

  for (int t = 0; t < TT; ++t) {
    const int par = t & 1;

    // ---- issue wx(t+1) loads now: ~1 full step of flight time
    {
      const int tn = (t + 1 < TT) ? t + 1 : t;
#pragma unroll
      for (int r = 0; r < 4; ++r) {
        size_t base = ((size_t)(row0 + 4 * q + r) * TT + tn) * TWOH + j;
        wxa_n[r] = wx[base];
        wxz_n[r] = wx[base + HH];
      }
    }

    // ---- tagged check + retry (first test is on the in-flight prefetch)
    {
      const u64* src = hxg + par * 4096 + tid;
      const u64 tagp = ((u64)(unsigned)t << 48) | ((u64)(unsigned)t << 16);
      bool ok = true;
#pragma unroll
      for (int pp = 0; pp < 8; ++pp) ok &= ((qw[pp] & TAGMASK) == tagp);
      int bail = 0;
      while (!__all(ok)) {
        __builtin_amdgcn_s_sleep(1);
#pragma unroll
        for (int pp = 0; pp < 8; ++pp)
          qw[pp] = __hip_atomic_load(src + (size_t)pp * 512, __ATOMIC_RELAXED,
                                     __HIP_MEMORY_SCOPE_AGENT);
        ok = true;
#pragma unroll
        for (int pp = 0; pp < 8; ++pp) ok &= ((qw[pp] & TAGMASK) == tagp);
        if (++bail > (1 << 15)) break;
      }
    }

    // ---- stage payload halves into XOR-swizzled LDS (rows mb+2*pp)
    {
      char* dst = hsm[par];
#pragma unroll
      for (int pp = 0; pp < 8; ++pp) {
        const int m = mb + pp * 2;
        unsigned d0 = (unsigned)qw[pp], d1 = (unsigned)(qw[pp] >> 32);
        unsigned pk = (d0 & 0xFFFFu) | (d1 << 16);
        *(unsigned*)(dst + ((m * 1024 + k2 * 4) ^ ((m & 7) << 4))) = pk;
      }
    }
    __syncthreads();

    // ---- MFMA: A row=l15, k-chunk q from LDS; both gate tiles
    f32x4 acc0 = {0.f, 0.f, 0.f, 0.f}, acc1 = {0.f, 0.f, 0.f, 0.f};
#pragma unroll
    for (int kb = 0; kb < KB; ++kb) {
      int off = (l15 * 1024 + kb * 64 + q * 16) ^ ((l15 & 7) << 4);
      f16x8 af = *(const f16x8*)(hsm[par] + off);
      acc0 = __builtin_amdgcn_mfma_f32_16x16x32_f16(af, bf[kb][0], acc0, 0, 0, 0);
      acc1 = __builtin_amdgcn_mfma_f32_16x16x32_f16(af, bf[kb][1], acc1, 0, 0, 0);
    }

    // ---- epilogue: tagged h stores FIRST (producer side, critical)
    unsigned* hd = hx + ((size_t)(g * 2 + (par ^ 1)) << 13);
    const unsigned tg = (unsigned)(t + 1) << 16;
    float atv[4], ztv[4], hcv[4];
#pragma unroll
    for (int r = 0; r < 4; ++r) {
      float at = acc0[r] + wxa[r];
      float zp = acc1[r] + wxz[r];
      float zt = 1.f / (1.f + __expf(-zp));
      float hc = fmaxf(at, 0.f) * mreg[r];
      float hn = hreg[r] * zt + (1.f - zt) * hc;
      hreg[r] = hn;
      __hip_atomic_store(hd + (4 * q + r) * HH + j,
                         tg | (unsigned)__half_as_ushort(__float2half(hn)),
                         __ATOMIC_RELAXED, __HIP_MEMORY_SCOPE_AGENT);
      atv[r] = at;
      ztv[r] = zt;
      hcv[r] = hc;
    }

    // ---- prefetch next parity (after h stores, before output stores)
    if (t + 1 < TT) {
      const u64* srcn = hxg + (par ^ 1) * 4096 + tid;
#pragma unroll
      for (int pp = 0; pp < 8; ++pp)
        qw[pp] = __hip_atomic_load(srcn + (size_t)pp * 512, __ATOMIC_RELAXED,
                                   __HIP_MEMORY_SCOPE_AGENT);
    }

    // ---- bulk outputs: fire-and-forget, newest in the vmcnt queue
#pragma unroll
    for (int r = 0; r < 4; ++r) {
      size_t oi = ((size_t)(row0 + 4 * q + r) * TT + t) * HH + j;
      __builtin_nontemporal_store(hreg[r], &out_h[oi]);
      __builtin_nontemporal_store(ztv[r], &out_z[oi]);
      __builtin_nontemporal_store(atv[r], &out_a[oi]);
      __builtin_nontemporal_store(hcv[r], &out_hc[oi]);
    }

    // ---- rotate wx double buffer (cheap register moves)
#pragma unroll
    for (int r = 0; r < 4; ++r) {
      wxa[r] = wxa_n[r];
      wxz[r] = wxz_n[r];
    }
    // hsm[par^1] is written next step only after this step's barrier.
  }
}

extern "C" void kernel_launch(void* const* d_in, const int* in_sizes, int n_in,
                              void* d_out, int out_size, void* d_ws,
                              size_t ws_size, hipStream_t stream) {
  const float* wx = (const float*)d_in[0];
  const float* u = (const float*)d_in[1];
  const float* ht = (const float*)d_in[2];
  const float* mask = (const float*)d_in[3];
  float* out = (float*)d_out;

  __half* u16 = (__half*)d_ws;
  unsigned* hx = (unsigned*)(u16 + WS_U16_HALVES);

  hipLaunchKernelGGL(prep_kernel, dim3(2048), dim3(256), 0, stream, u, ht, u16,
                     hx);
  hipLaunchKernelGGL(ligru_mfma, dim3(32), dim3(512), 0, stream, wx, u16, ht,
                     mask, out, hx);
}

// Round 14
// 1384.054 us; speedup vs baseline: 1.4081x; 1.4081x over previous
//
#include <hip/hip_runtime.h>
#include <hip/hip_fp16.h>

#define BB 128
#define TT 500
#define HH 512
#define TWOH 1024
#define KB 16  // k-tiles of 32

typedef _Float16 f16x8 __attribute__((ext_vector_type(8)));
typedef float f32x4 __attribute__((ext_vector_type(4)));
typedef unsigned long long u64;

// ws: u16 1 MiB | hx u32 [8 g][2 par][16 m][512 k] (512 KiB)
// hx word = (tag16 << 16) | fp16 h[m][k]   (tag = step, 0..500; 0xFFFF = inv)
#define WS_U16_HALVES (TWOH * HH)
#define HX_WORDS (8 * 2 * 16 * HH)

__global__ void prep_kernel(const float* __restrict__ u,
                            const float* __restrict__ ht,
                            __half* __restrict__ u16,
                            unsigned* __restrict__ hx) {
  int i = blockIdx.x * blockDim.x + threadIdx.x;
  if (i < WS_U16_HALVES) u16[i] = __float2half(u[i]);
  if (i < HX_WORDS) {
    int g = i >> 14, rem = i & 16383;
    int par = rem >> 13, m = (rem >> 9) & 15, k = rem & 511;
    unsigned val;
    if (par == 0) {  // h_0, tag 0 in high halfword
      int R = g * 16 + m;
      val = (unsigned)__half_as_ushort(__float2half(ht[(size_t)R * HH + k]));
    } else {
      val = 0xFFFF0000u;  // sentinel (never matches; replay-stale safe)
    }
    hx[i] = val;
  }
}

#define TAGMASK 0xFFFF0000FFFF0000ull

// 64 blocks x 256 threads (4 waves). Block b: group g=b>>3 (16 batch rows),
// col-slice s=b&7 (64 cols, both gates). One chain-phase per step; MALL
// (agent-scope) fused tag16+fp16 protocol — the cooperative tagged read IS
// the flag poll AND the payload fetch (proven R7/R10). R14: own-slice h
// bypasses the MALL entirely (epilogue writes it straight into next-parity
// LDS; the 32 threads whose staged qwords are own-slice skip load+check),
// first retry is immediate (no sleep), wx is double-buffered.
__global__ __launch_bounds__(256, 1) void ligru_mfma(
    const float* __restrict__ wx, const __half* __restrict__ u16,
    const float* __restrict__ ht, const float* __restrict__ mask,
    float* __restrict__ out, unsigned* __restrict__ hx) {
  const int tid = threadIdx.x;
  const int lane = tid & 63;
  const int w = tid >> 6;
  const int l15 = lane & 15;
  const int q = lane >> 4;
  const int b = blockIdx.x;
  const int g = b >> 3;
  const int s = b & 7;
  const int row0 = g * 16;
  const int j = s * 64 + w * 16 + l15;  // this lane's hidden col

  // thread's staged qword column = tid (k-dwords 2*tid, 2*tid+1).
  // own-slice <=> both k-cols in [s*64, s*64+64) <=> tid in [s*32, s*32+32)
  const bool own = (tid >= s * 32) && (tid < s * 32 + 32);

  __shared__ alignas(16) char hsm[2][16 * 1024];  // [par][m][k] fp16, XOR-swz

  // B-frags (u), persistent (128 VGPR). nt0: gate row j (at); nt1: row 512+j.
  f16x8 bf[KB][2];
#pragma unroll
  for (int kb = 0; kb < KB; ++kb) {
    bf[kb][0] = *(const f16x8*)(u16 + (size_t)j * HH + kb * 32 + q * 8);
    bf[kb][1] = *(const f16x8*)(u16 + (size_t)(HH + j) * HH + kb * 32 + q * 8);
  }

  // per-lane persistent state: rows m=4q+r, col j; fp32 master h
  float hreg[4], mreg[4];
#pragma unroll
  for (int r = 0; r < 4; ++r) {
    size_t off = (size_t)(row0 + 4 * q + r) * HH + j;
    mreg[r] = mask[off];
    hreg[r] = ht[off];
  }

  const size_t BTH = (size_t)BB * TT * HH;
  float* out_h = out;
  float* out_z = out + BTH;
  float* out_a = out + 2 * BTH;
  float* out_hc = out + 3 * BTH;

  const u64* hxg = (const u64*)hx + ((size_t)g << 13);  // [2 par][4096 qw]

  // initial fetch: h(0), parity 0, written by prep with tag 0 (everyone,
  // including own-slice threads: t=0 LDS comes from hx, not direct-writes)
  u64 qw[16];
#pragma unroll
  for (int pp = 0; pp < 16; ++pp)
    qw[pp] = __hip_atomic_load(hxg + pp * 256 + tid, __ATOMIC_RELAXED,
                               __HIP_MEMORY_SCOPE_AGENT);

  // wx double buffer: cur = step t (in regs), nxt in flight for t+1
  float wxa[4], wxz[4], wxa_n[4], wxz_n[4];
#pragma unroll
  for (int r = 0; r < 4; ++r) {
    size_t base = (size_t)(row0 + 4 * q + r) * TT * TWOH + j;
    wxa[r] = wx[base];
    wxz[r] = wx[base + HH];
  }

  for (int t = 0; t < TT; ++t) {
    const int par = t & 1;

    // ---- issue wx(t+1): ~1 full step of flight time
    {
      const int tn = (t + 1 < TT) ? t + 1 : t;
#pragma unroll
      for (int r = 0; r < 4; ++r) {
        size_t base = ((size_t)(row0 + 4 * q + r) * TT + tn) * TWOH + j;
        wxa_n[r] = wx[base];
        wxz_n[r] = wx[base + HH];
      }
    }

    // ---- tagged check + retry (own-slice threads auto-pass for t>0:
    // their data arrives via the epilogue's direct LDS writes)
    {
      const bool skip = own && (t > 0);
      const u64* src = hxg + par * 4096 + tid;
      const u64 tagp = ((u64)(unsigned)t << 48) | ((u64)(unsigned)t << 16);
      bool ok = true;
#pragma unroll
      for (int pp = 0; pp < 16; ++pp) ok &= ((qw[pp] & TAGMASK) == tagp);
      ok |= skip;
      if (!__all(ok)) {
        // immediate first retry: producers typically landed within the
        // check's own latency window
        if (!skip) {
#pragma unroll
          for (int pp = 0; pp < 16; ++pp)
            qw[pp] = __hip_atomic_load(src + pp * 256, __ATOMIC_RELAXED,
                                       __HIP_MEMORY_SCOPE_AGENT);
          ok = true;
#pragma unroll
          for (int pp = 0; pp < 16; ++pp) ok &= ((qw[pp] & TAGMASK) == tagp);
        }
        int bail = 0;
        while (!__all(ok)) {
          __builtin_amdgcn_s_sleep(1);
          if (!skip) {
#pragma unroll
            for (int pp = 0; pp < 16; ++pp)
              qw[pp] = __hip_atomic_load(src + pp * 256, __ATOMIC_RELAXED,
                                         __HIP_MEMORY_SCOPE_AGENT);
            ok = true;
#pragma unroll
            for (int pp = 0; pp < 16; ++pp) ok &= ((qw[pp] & TAGMASK) == tagp);
          }
          if (++bail > (1 << 15)) break;
        }
      }
    }

    // ---- stage remote payload into XOR-swizzled LDS (own-slice t>0: the
    // direct writes from step t-1's epilogue already populated these bytes)
    if (!(own && t > 0)) {
      char* dst = hsm[par];
#pragma unroll
      for (int pp = 0; pp < 16; ++pp) {
        unsigned d0 = (unsigned)qw[pp], d1 = (unsigned)(qw[pp] >> 32);
        unsigned pk = (d0 & 0xFFFFu) | (d1 << 16);
        *(unsigned*)(dst + ((pp * 1024 + tid * 4) ^ ((pp & 7) << 4))) = pk;
      }
    }
    __syncthreads();

    // ---- MFMA: A row=l15, k-chunk q from LDS; both gate tiles
    f32x4 acc0 = {0.f, 0.f, 0.f, 0.f}, acc1 = {0.f, 0.f, 0.f, 0.f};
#pragma unroll
    for (int kb = 0; kb < KB; ++kb) {
      int off = (l15 * 1024 + kb * 64 + q * 16) ^ ((l15 & 7) << 4);
      f16x8 af = *(const f16x8*)(hsm[par] + off);
      acc0 = __builtin_amdgcn_mfma_f32_16x16x32_f16(af, bf[kb][0], acc0, 0, 0, 0);
      acc1 = __builtin_amdgcn_mfma_f32_16x16x32_f16(af, bf[kb][1], acc1, 0, 0, 0);
    }

    // ---- epilogue: tagged h stores FIRST (producer side, critical)
    unsigned* hd = hx + ((size_t)(g * 2 + (par ^ 1)) << 13);
    const unsigned tg = (unsigned)(t + 1) << 16;
    char* ldst = hsm[par ^ 1];
    float atv[4], ztv[4], hcv[4];
    __half hh[4];
#pragma unroll
    for (int r = 0; r < 4; ++r) {
      float at = acc0[r] + wxa[r];
      float zp = acc1[r] + wxz[r];
      float zt = 1.f / (1.f + __expf(-zp));
      float hc = fmaxf(at, 0.f) * mreg[r];
      float hn = hreg[r] * zt + (1.f - zt) * hc;
      hreg[r] = hn;
      hh[r] = __float2half(hn);
      __hip_atomic_store(hd + (4 * q + r) * HH + j,
                         tg | (unsigned)__half_as_ushort(hh[r]),
                         __ATOMIC_RELAXED, __HIP_MEMORY_SCOPE_AGENT);
      atv[r] = at;
      ztv[r] = zt;
      hcv[r] = hc;
    }

    // ---- own-slice direct LDS write for next parity (bypasses the MALL;
    // also delays the prefetch sampling point -> fresher tags on arrival)
#pragma unroll
    for (int r = 0; r < 4; ++r) {
      const int m = 4 * q + r;
      *(__half*)(ldst + ((m * 1024 + j * 2) ^ ((m & 7) << 4))) = hh[r];
    }

    // ---- prefetch next parity (after h stores, before output stores;
    // own-slice threads never need it again after t=0)
    if (t + 1 < TT && !own) {
      const u64* srcn = hxg + (par ^ 1) * 4096 + tid;
#pragma unroll
      for (int pp = 0; pp < 16; ++pp)
        qw[pp] = __hip_atomic_load(srcn + pp * 256, __ATOMIC_RELAXED,
                                   __HIP_MEMORY_SCOPE_AGENT);
    }

    // ---- bulk outputs: fire-and-forget, newest in the vmcnt queue
#pragma unroll
    for (int r = 0; r < 4; ++r) {
      size_t oi = ((size_t)(row0 + 4 * q + r) * TT + t) * HH + j;
      __builtin_nontemporal_store(hreg[r], &out_h[oi]);
      __builtin_nontemporal_store(ztv[r], &out_z[oi]);
      __builtin_nontemporal_store(atv[r], &out_a[oi]);
      __builtin_nontemporal_store(hcv[r], &out_hc[oi]);
    }

    // ---- rotate wx double buffer
#pragma unroll
    for (int r = 0; r < 4; ++r) {
      wxa[r] = wxa_n[r];
      wxz[r] = wxz_n[r];
    }
    // hsm[par^1] remote portion is staged next step only after this step's
    // barrier; own portion was written above (ordered by the same barrier).
  }
}

extern "C" void kernel_launch(void* const* d_in, const int* in_sizes, int n_in,
                              void* d_out, int out_size, void* d_ws,
                              size_t ws_size, hipStream_t stream) {
  const float* wx = (const float*)d_in[0];
  const float* u = (const float*)d_in[1];
  const float* ht = (const float*)d_in[2];
  const float* mask = (const float*)d_in[3];
  float* out = (float*)d_out;

  __half* u16 = (__half*)d_ws;
  unsigned* hx = (unsigned*)(u16 + WS_U16_HALVES);

  hipLaunchKernelGGL(prep_kernel, dim3(2048), dim3(256), 0, stream, u, ht, u16,
                     hx);
  hipLaunchKernelGGL(ligru_mfma, dim3(64), dim3(256), 0, stream, wx, u16, ht,
                     mask, out, hx);
}